// Round 3
// baseline (100.674 us; speedup 1.0000x reference)
//
#include <hip/hip_runtime.h>
#include <hip/hip_bf16.h>
#include <math.h>

// ---------------------------------------------------------------------------
// PointerNet attention scorer, MI355X / gfx950.
//   1) proj_gemm: C = exp2(scale*(A@W^T + bias)) on bf16 MFMA with in-staging
//      fp32->bf16 hi/lo split (3 passes: hiA*hiW + hiA*loW + loA*hiW,
//      rel err ~2^-16). Tile 64m x 64n, 384 blocks, 256 thr, single-buffered
//      LDS. src -> spq h-quad-interleaved, query -> qp row-major. Epilogue
//      stores exp2(val): exp2(a+b)=exp2(a)*exp2(b) hoists 67M exp2 out of
//      attn_score.
//      R5: XCD-aware work remap — dispatch round-robins linear bid across
//      8 XCDs (bid&7 = XCD); remap so each XCD owns 12 m-blocks x all 4 nb
//      -> A rows fetched once per XCD L2 (was 4x via L3), W 1 MB/XCD.
//   2) attn_score: logit ~ -2*sum_h w2[h]/(es*eq+1), masked softmax, S=128.
//      Mask compaction (execz skip when nU<=64) + pair-2 rcp.
//      R5: XCD remap — 16 same-b blocks (sharing a 128 KB spq slice) now
//      land on one XCD -> spq served from L2 (~16x reuse), L3 traffic
//      67 MB -> ~4-8 MB. R2 showed attn is not issue-bound; theory: it is
//      L3-BW bound on the spq re-reads.
// ---------------------------------------------------------------------------

#define TANH_PRESCALE 2.8853900817779268f   // 2*log2(e)
#define LOG2E        1.4426950408889634f

typedef __attribute__((ext_vector_type(8))) short short8;   // 8 bf16 = 4 VGPR
typedef __attribute__((ext_vector_type(4))) float f32x4;    // MFMA C/D frag

__device__ __forceinline__ float fast_exp2(float x) {
#if __has_builtin(__builtin_amdgcn_exp2f)
    return __builtin_amdgcn_exp2f(x);
#else
    return exp2f(x);
#endif
}
__device__ __forceinline__ float fast_rcp(float x) {
#if __has_builtin(__builtin_amdgcn_rcpf)
    return __builtin_amdgcn_rcpf(x);
#else
    return 1.0f / x;
#endif
}
__device__ __forceinline__ float hi_part(float x) {   // truncate to bf16 grid
    return __uint_as_float(__float_as_uint(x) & 0xffff0000u);
}
// pack bf16(a)=low16, bf16(b)=high16 (truncating) in one v_perm
__device__ __forceinline__ unsigned pack2(float a, float b) {
    return __builtin_amdgcn_perm(__float_as_uint(b), __float_as_uint(a), 0x07060302u);
}

// ---------------------------------------------------------------------------
// proj_gemm — R2-proven mechanics + XCD work remap.
// ---------------------------------------------------------------------------
#define AHI 0
#define ALO 4608            // 64*72
#define WHI 9216
#define WLO 13824
#define LDS_USH 18432       // 36864 B

__global__ __launch_bounds__(256) void proj_gemm(
    const float* __restrict__ src, const float* __restrict__ query,
    const float* __restrict__ Wsrc, const float* __restrict__ Wq,
    const float* __restrict__ b_src, const float* __restrict__ b_q,
    float* __restrict__ spq, float* __restrict__ qp)
{
    // XCD remap: bid&7 = XCD (round-robin dispatch). w bijective on [0,384).
    // XCD k owns w in [48k,48k+48) -> m-blocks [12k,12k+12) x all 4 nb.
    const int bid = blockIdx.x;       // 0..383
    const int w   = (bid & 7) * 48 + (bid >> 3);
    const int bx  = w >> 2;           // 0..95  (m-block)
    const int nb  = w & 3;            // 0..3   (n-block)
    const bool isSrc = bx < 64;
    const int mrow0 = (isSrc ? bx : bx - 64) * 64;
    const float* __restrict__ A    = isSrc ? src  : query;
    const float* __restrict__ W    = isSrc ? Wsrc : Wq;
    const float* __restrict__ bias = isSrc ? b_src : b_q;

    __shared__ unsigned short LS[LDS_USH];

    const int tid  = threadIdx.x;
    const int lane = tid & 63;
    const int wv   = tid >> 6;
    const int wm   = wv & 1, wn = wv >> 1;
    const int l15  = lane & 15;
    const int q4   = lane >> 4;       // 0..3

    const int srow = tid >> 3;        // rows for p=0 (0..31); p=1 adds 32
    const int sc8  = tid & 7;

    f32x4 acc[2][2];
    #pragma unroll
    for (int i = 0; i < 2; ++i)
        #pragma unroll
        for (int j = 0; j < 2; ++j) acc[i][j] = (f32x4){0.f, 0.f, 0.f, 0.f};

    const float* Ab = A + (size_t)mrow0 * 512 + sc8 * 8;
    const float* Wb = W + (size_t)(nb * 64) * 512 + sc8 * 8;

    for (int kt = 0; kt < 512; kt += 64) {
        __syncthreads();   // previous tile's frag reads done
        #pragma unroll
        for (int p = 0; p < 2; ++p) {          // A: 64 rows x 64 k
            const int row = srow + 32 * p;
            const float* g = Ab + (size_t)row * 512 + kt;
            float4 v0 = *(const float4*)g, v1 = *(const float4*)(g + 4);
            uint4 h; uint4 l;
            h.x = pack2(v0.x, v0.y);  h.y = pack2(v0.z, v0.w);
            h.z = pack2(v1.x, v1.y);  h.w = pack2(v1.z, v1.w);
            l.x = pack2(v0.x - hi_part(v0.x), v0.y - hi_part(v0.y));
            l.y = pack2(v0.z - hi_part(v0.z), v0.w - hi_part(v0.w));
            l.z = pack2(v1.x - hi_part(v1.x), v1.y - hi_part(v1.y));
            l.w = pack2(v1.z - hi_part(v1.z), v1.w - hi_part(v1.w));
            *(uint4*)&LS[AHI + row * 72 + sc8 * 8] = h;
            *(uint4*)&LS[ALO + row * 72 + sc8 * 8] = l;
        }
        #pragma unroll
        for (int p = 0; p < 2; ++p) {          // W: 64 rows x 64 k
            const int row = srow + 32 * p;
            const float* g = Wb + (size_t)row * 512 + kt;
            float4 v0 = *(const float4*)g, v1 = *(const float4*)(g + 4);
            uint4 h; uint4 l;
            h.x = pack2(v0.x, v0.y);  h.y = pack2(v0.z, v0.w);
            h.z = pack2(v1.x, v1.y);  h.w = pack2(v1.z, v1.w);
            l.x = pack2(v0.x - hi_part(v0.x), v0.y - hi_part(v0.y));
            l.y = pack2(v0.z - hi_part(v0.z), v0.w - hi_part(v0.w));
            l.z = pack2(v1.x - hi_part(v1.x), v1.y - hi_part(v1.y));
            l.w = pack2(v1.z - hi_part(v1.z), v1.w - hi_part(v1.w));
            *(uint4*)&LS[WHI + row * 72 + sc8 * 8] = h;
            *(uint4*)&LS[WLO + row * 72 + sc8 * 8] = l;
        }
        __syncthreads();

        #pragma unroll
        for (int pass = 0; pass < 3; ++pass) {
            const unsigned short* Ap = LS + (pass == 2 ? ALO : AHI);
            const unsigned short* Wp = LS + (pass == 1 ? WLO : WHI);
            #pragma unroll
            for (int kk = 0; kk < 2; ++kk) {
                const int off = (kk * 4 + q4) * 8;    // ushort k-octet offset
                short8 a0 = *(const short8*)&Ap[(wm * 32 + l15)      * 72 + off];
                short8 a1 = *(const short8*)&Ap[(wm * 32 + 16 + l15) * 72 + off];
                short8 w0 = *(const short8*)&Wp[(wn * 32 + l15)      * 72 + off];
                short8 w1 = *(const short8*)&Wp[(wn * 32 + 16 + l15) * 72 + off];
                acc[0][0] = __builtin_amdgcn_mfma_f32_16x16x32_bf16(a0, w0, acc[0][0], 0, 0, 0);
                acc[0][1] = __builtin_amdgcn_mfma_f32_16x16x32_bf16(a0, w1, acc[0][1], 0, 0, 0);
                acc[1][0] = __builtin_amdgcn_mfma_f32_16x16x32_bf16(a1, w0, acc[1][0], 0, 0, 0);
                acc[1][1] = __builtin_amdgcn_mfma_f32_16x16x32_bf16(a1, w1, acc[1][1], 0, 0, 0);
            }
        }
    }

    float bl[2];
    #pragma unroll
    for (int ni = 0; ni < 2; ++ni)
        bl[ni] = bias[nb * 64 + wn * 32 + ni * 16 + l15];

    __syncthreads();                 // frag reads done before E overwrites LDS
    float* E = (float*)LS;           // 64 x 68 fp32 = 17408 B
    #pragma unroll
    for (int mi = 0; mi < 2; ++mi)
        #pragma unroll
        for (int ni = 0; ni < 2; ++ni) {
            const int m = wm * 32 + mi * 16 + q4 * 4;   // C/D: row=(lane>>4)*4+r
            const int n = wn * 32 + ni * 16 + l15;      //      col=lane&15
            #pragma unroll
            for (int r = 0; r < 4; ++r)
                E[(m + r) * 68 + n] =
                    fast_exp2((acc[mi][ni][r] + bl[ni]) * TANH_PRESCALE);
        }
    __syncthreads();

    if (isSrc) {
        // h-quad-interleaved: spq[(nb*16+nq)*16384 + (mrow0+m)*4 + (n&3)]
        const int nq = tid >> 4;                     // 0..15
        #pragma unroll
        for (int j = 0; j < 4; ++j) {
            const int m = (tid & 15) + 16 * j;       // 0..63
            float4 v = *(const float4*)&E[m * 68 + nq * 4];
            *(float4*)(spq + (size_t)(nb * 16 + nq) * 16384
                           + (size_t)(mrow0 + m) * 4) = v;
        }
    } else {
        // row-major qp[(mrow0+m)*256 + nb*64 + n]
        #pragma unroll
        for (int p = 0; p < 4; ++p) {
            const int idx = p * 256 + tid;
            const int m = idx >> 4, c4 = idx & 15;
            float4 v = *(const float4*)&E[m * 68 + c4 * 4];
            *(float4*)(qp + (size_t)(mrow0 + m) * 256 + nb * 64 + c4 * 4) = v;
        }
    }
}

// ---------------------------------------------------------------------------
// Fused score + masked softmax. 512 blocks x 512 thr (8 waves).
// XCD remap: each XCD owns 4 consecutive b's -> the 16 same-b blocks share
// one L2 and re-read the 128 KB spq b-slice from L2, not L3.
// Mask-compacted s slots + pair-2 rcp fusion.
// ---------------------------------------------------------------------------
__global__ __launch_bounds__(512) void attn_score(
    const float* __restrict__ spq, const float* __restrict__ qp,
    const float* __restrict__ w2, const int* __restrict__ mask,
    float* __restrict__ out)
{
    // bid&7 = XCD; XCD k owns w in [64k,64k+64) -> b in [4k,4k+4).
    const int bid = blockIdx.x;        // 0..511
    const int w   = (bid & 7) * 64 + (bid >> 3);
    const int b   = w >> 4;            // 0..31
    const int tz  = w & 15;            // 0..15
    const int tid = threadIdx.x;

    __shared__ float qp_s[4][256];
    __shared__ float w2_s[256];
    __shared__ float h2p[4][4][128];   // [h-group][t-local][compacted s]
    __shared__ int   list_s[128];      // compacted -> original s
    __shared__ int   inv_s[128];       // original s -> compacted (-1 masked)
    __shared__ int   cnt_s[2];
    __shared__ int   nU_s;

    // --- staging: qp rows, w2, mask ballot-compaction ---
    int keep = 0, pre = 0, w01 = 0;
    if (tid < 256) {
        const int tl = tid >> 6, lane = tid & 63;
        const int t = tz * 4 + tl;
        *(float4*)&qp_s[tl][lane * 4] =
            *(const float4*)(qp + (size_t)(t * 32 + b) * 256 + lane * 4);
    } else if (tid < 320) {
        const int i = tid - 256;
        *(float4*)&w2_s[i * 4] = *(const float4*)(w2 + i * 4);
    }
    if (tid < 128) {                       // waves 0,1 fully present
        w01  = tid >> 6;
        keep = !mask[b * 128 + tid];
        const unsigned long long bal = __ballot(keep);
        pre  = __popcll(bal & ((1ull << (tid & 63)) - 1ull));
        if ((tid & 63) == 0) cnt_s[w01] = (int)__popcll(bal);
        inv_s[tid] = -1;
    }
    __syncthreads();
    if (tid < 128 && keep) {
        const int pos = (w01 ? cnt_s[0] : 0) + pre;
        list_s[pos] = tid;
        inv_s[tid]  = pos;
    }
    if (tid == 0) nU_s = cnt_s[0] + cnt_s[1];
    __syncthreads();

    const int j  = tid & 127;          // compacted s slot
    const int g  = tid >> 7;           // 0..3 -> h in [g*64, g*64+64)
    const int hb = g * 64;
    const int nU = nU_s;

    if (j < nU) {                      // whole-wave execz skip when nU<=64
        const int s = list_s[j];
        const float* sq = spq + (size_t)(g * 16) * 16384
                              + (size_t)(b * 128 + s) * 4;

        float acc0 = 0.f, acc1 = 0.f, acc2 = 0.f, acc3 = 0.f;
        float4 s4 = *(const float4*)sq;                 // prefetch hq=0
        #pragma unroll 4
        for (int hq = 0; hq < 16; ++hq) {
            float4 nxt;
            if (hq < 15) nxt = *(const float4*)(sq + (size_t)(hq + 1) * 16384);
            float4 w4 = *(const float4*)&w2_s[hb + hq * 4];
            float4 q0 = *(const float4*)&qp_s[0][hb + hq * 4];
            float4 q1 = *(const float4*)&qp_s[1][hb + hq * 4];
            float4 q2 = *(const float4*)&qp_s[2][hb + hq * 4];
            float4 q3 = *(const float4*)&qp_s[3][hb + hq * 4];
            // pair-2: w0/d0 + w1/d1 = (w0*d1 + w1*d0) * rcp(d0*d1)
            #define PN_PAIR(sa, sb, wa, wb, qa, qb, accv)                     \
                { float da = fmaf(sa, qa, 1.0f);                              \
                  float db = fmaf(sb, qb, 1.0f);                              \
                  float nm = fmaf(wa, db, wb * da);                           \
                  accv = fmaf(nm, fast_rcp(da * db), accv); }
            PN_PAIR(s4.x, s4.y, w4.x, w4.y, q0.x, q0.y, acc0)
            PN_PAIR(s4.x, s4.y, w4.x, w4.y, q1.x, q1.y, acc1)
            PN_PAIR(s4.x, s4.y, w4.x, w4.y, q2.x, q2.y, acc2)
            PN_PAIR(s4.x, s4.y, w4.x, w4.y, q3.x, q3.y, acc3)
            PN_PAIR(s4.z, s4.w, w4.z, w4.w, q0.z, q0.w, acc0)
            PN_PAIR(s4.z, s4.w, w4.z, w4.w, q1.z, q1.w, acc1)
            PN_PAIR(s4.z, s4.w, w4.z, w4.w, q2.z, q2.w, acc2)
            PN_PAIR(s4.z, s4.w, w4.z, w4.w, q3.z, q3.w, acc3)
            #undef PN_PAIR
            s4 = nxt;
        }
        h2p[g][0][j] = acc0;
        h2p[g][1][j] = acc1;
        h2p[g][2][j] = acc2;
        h2p[g][3][j] = acc3;
    }
    __syncthreads();

    if (tid < 256) {
        const int wv = tid >> 6, lane = tid & 63;
        const int j0 = inv_s[lane], j1 = inv_s[lane + 64];
        float v0 = -__builtin_inff(), v1 = -__builtin_inff();
        if (j0 >= 0) v0 = -2.0f * (h2p[0][wv][j0] + h2p[1][wv][j0]
                                 + h2p[2][wv][j0] + h2p[3][wv][j0]);
        if (j1 >= 0) v1 = -2.0f * (h2p[0][wv][j1] + h2p[1][wv][j1]
                                 + h2p[2][wv][j1] + h2p[3][wv][j1]);

        float mx = fmaxf(v0, v1);
        #pragma unroll
        for (int off = 32; off >= 1; off >>= 1) mx = fmaxf(mx, __shfl_xor(mx, off));
        float e0 = fast_exp2((v0 - mx) * LOG2E);   // -inf -> 0
        float e1 = fast_exp2((v1 - mx) * LOG2E);
        float sum = e0 + e1;
        #pragma unroll
        for (int off = 32; off >= 1; off >>= 1) sum += __shfl_xor(sum, off);
        const float r = fast_rcp(sum);

        const size_t ob = (size_t)((tz * 4 + wv) * 32 + b) * 128;
        out[ob + lane]      = e0 * r;
        out[ob + lane + 64] = e1 * r;
    }
}

extern "C" void kernel_launch(void* const* d_in, const int* in_sizes, int n_in,
                              void* d_out, int out_size, void* d_ws, size_t ws_size,
                              hipStream_t stream) {
    const float* src   = (const float*)d_in[0];   // (B,S,E)
    const int*   mask  = (const int*)  d_in[1];   // (B,S)
    const float* query = (const float*)d_in[2];   // (T,B,Q)
    const float* W_src = (const float*)d_in[3];   // (H,E)
    const float* b_src = (const float*)d_in[4];
    const float* W_q   = (const float*)d_in[5];   // (H,Q)
    const float* b_q   = (const float*)d_in[6];
    const float* w2    = (const float*)d_in[7];
    // d_in[8] = b2 : unused (softmax shift-invariant)
    float* out = (float*)d_out;

    // ws: spq 4 MB @0 | qp 2 MB @4MB  (minimal footprint — ws is poisoned
    // with 256 MB of 0xAA every iteration; extra ws traffic is cold misses)
    float* spq = (float*)d_ws;
    float* qp  = (float*)((char*)d_ws + (4u << 20));

    proj_gemm<<<dim3(384), 256, 0, stream>>>(src, query, W_src, W_q,
                                             b_src, b_q, spq, qp);
    attn_score<<<dim3(512), 512, 0, stream>>>(spq, qp, w2, mask, out);
}

// Round 4
// 99.510 us; speedup vs baseline: 1.0117x; 1.0117x over previous
//
#include <hip/hip_runtime.h>
#include <hip/hip_bf16.h>
#include <math.h>

// ---------------------------------------------------------------------------
// PointerNet attention scorer, MI355X / gfx950.
//   1) proj_gemm: C = exp2(scale*(A@W^T + bias)) on bf16 MFMA with in-staging
//      fp32->bf16 hi/lo split (3 passes: hiA*hiW + hiA*loW + loA*hiW,
//      rel err ~2^-16). Tile 64m x 64n, grid (96,4), 256 thr, single-buffered
//      LDS. src -> spq h-quad-interleaved, query -> qp row-major. Epilogue
//      stores exp2(val): exp2(a+b)=exp2(a)*exp2(b) hoists 67M exp2 out of
//      attn_score.
//      R6: R3's XCD remap REVERTED (+4.5us regression) — 2-D grid already
//      co-locates reuse-sharing blocks per XCD (same-b stride 32 ≡ 0 mod 8;
//      same-bx stride 96 ≡ 0 mod 8).
//   2) attn_score: logit ~ -2*sum_h w2[h]/(es*eq+1), masked softmax, S=128.
//      Mask compaction (execz skip when nU<=64) + pair-2 rcp.
//      R6: 4-deep named-register prefetch on the 64KB-strided spq loads
//      (R2 showed attn is latency-bound, not issue-bound: 16 chained L3
//      loads x ~400-600cy with only 1 body of hiding). Static p0..p3 regs,
//      fully unrolled hq loop (no runtime-indexed arrays -> no scratch).
// ---------------------------------------------------------------------------

#define TANH_PRESCALE 2.8853900817779268f   // 2*log2(e)
#define LOG2E        1.4426950408889634f

typedef __attribute__((ext_vector_type(8))) short short8;   // 8 bf16 = 4 VGPR
typedef __attribute__((ext_vector_type(4))) float f32x4;    // MFMA C/D frag

__device__ __forceinline__ float fast_exp2(float x) {
#if __has_builtin(__builtin_amdgcn_exp2f)
    return __builtin_amdgcn_exp2f(x);
#else
    return exp2f(x);
#endif
}
__device__ __forceinline__ float fast_rcp(float x) {
#if __has_builtin(__builtin_amdgcn_rcpf)
    return __builtin_amdgcn_rcpf(x);
#else
    return 1.0f / x;
#endif
}
__device__ __forceinline__ float hi_part(float x) {   // truncate to bf16 grid
    return __uint_as_float(__float_as_uint(x) & 0xffff0000u);
}
// pack bf16(a)=low16, bf16(b)=high16 (truncating) in one v_perm
__device__ __forceinline__ unsigned pack2(float a, float b) {
    return __builtin_amdgcn_perm(__float_as_uint(b), __float_as_uint(a), 0x07060302u);
}

// ---------------------------------------------------------------------------
// proj_gemm — R2-proven mechanics, original 2-D grid (96,4).
// ---------------------------------------------------------------------------
#define AHI 0
#define ALO 4608            // 64*72
#define WHI 9216
#define WLO 13824
#define LDS_USH 18432       // 36864 B

__global__ __launch_bounds__(256) void proj_gemm(
    const float* __restrict__ src, const float* __restrict__ query,
    const float* __restrict__ Wsrc, const float* __restrict__ Wq,
    const float* __restrict__ b_src, const float* __restrict__ b_q,
    float* __restrict__ spq, float* __restrict__ qp)
{
    const int bx = blockIdx.x;        // 0..95
    const int nb = blockIdx.y;        // 0..3
    const bool isSrc = bx < 64;
    const int mrow0 = (isSrc ? bx : bx - 64) * 64;
    const float* __restrict__ A    = isSrc ? src  : query;
    const float* __restrict__ W    = isSrc ? Wsrc : Wq;
    const float* __restrict__ bias = isSrc ? b_src : b_q;

    __shared__ unsigned short LS[LDS_USH];

    const int tid  = threadIdx.x;
    const int lane = tid & 63;
    const int wv   = tid >> 6;
    const int wm   = wv & 1, wn = wv >> 1;
    const int l15  = lane & 15;
    const int q4   = lane >> 4;       // 0..3

    const int srow = tid >> 3;        // rows for p=0 (0..31); p=1 adds 32
    const int sc8  = tid & 7;

    f32x4 acc[2][2];
    #pragma unroll
    for (int i = 0; i < 2; ++i)
        #pragma unroll
        for (int j = 0; j < 2; ++j) acc[i][j] = (f32x4){0.f, 0.f, 0.f, 0.f};

    const float* Ab = A + (size_t)mrow0 * 512 + sc8 * 8;
    const float* Wb = W + (size_t)(nb * 64) * 512 + sc8 * 8;

    for (int kt = 0; kt < 512; kt += 64) {
        __syncthreads();   // previous tile's frag reads done
        #pragma unroll
        for (int p = 0; p < 2; ++p) {          // A: 64 rows x 64 k
            const int row = srow + 32 * p;
            const float* g = Ab + (size_t)row * 512 + kt;
            float4 v0 = *(const float4*)g, v1 = *(const float4*)(g + 4);
            uint4 h; uint4 l;
            h.x = pack2(v0.x, v0.y);  h.y = pack2(v0.z, v0.w);
            h.z = pack2(v1.x, v1.y);  h.w = pack2(v1.z, v1.w);
            l.x = pack2(v0.x - hi_part(v0.x), v0.y - hi_part(v0.y));
            l.y = pack2(v0.z - hi_part(v0.z), v0.w - hi_part(v0.w));
            l.z = pack2(v1.x - hi_part(v1.x), v1.y - hi_part(v1.y));
            l.w = pack2(v1.z - hi_part(v1.z), v1.w - hi_part(v1.w));
            *(uint4*)&LS[AHI + row * 72 + sc8 * 8] = h;
            *(uint4*)&LS[ALO + row * 72 + sc8 * 8] = l;
        }
        #pragma unroll
        for (int p = 0; p < 2; ++p) {          // W: 64 rows x 64 k
            const int row = srow + 32 * p;
            const float* g = Wb + (size_t)row * 512 + kt;
            float4 v0 = *(const float4*)g, v1 = *(const float4*)(g + 4);
            uint4 h; uint4 l;
            h.x = pack2(v0.x, v0.y);  h.y = pack2(v0.z, v0.w);
            h.z = pack2(v1.x, v1.y);  h.w = pack2(v1.z, v1.w);
            l.x = pack2(v0.x - hi_part(v0.x), v0.y - hi_part(v0.y));
            l.y = pack2(v0.z - hi_part(v0.z), v0.w - hi_part(v0.w));
            l.z = pack2(v1.x - hi_part(v1.x), v1.y - hi_part(v1.y));
            l.w = pack2(v1.z - hi_part(v1.z), v1.w - hi_part(v1.w));
            *(uint4*)&LS[WHI + row * 72 + sc8 * 8] = h;
            *(uint4*)&LS[WLO + row * 72 + sc8 * 8] = l;
        }
        __syncthreads();

        #pragma unroll
        for (int pass = 0; pass < 3; ++pass) {
            const unsigned short* Ap = LS + (pass == 2 ? ALO : AHI);
            const unsigned short* Wp = LS + (pass == 1 ? WLO : WHI);
            #pragma unroll
            for (int kk = 0; kk < 2; ++kk) {
                const int off = (kk * 4 + q4) * 8;    // ushort k-octet offset
                short8 a0 = *(const short8*)&Ap[(wm * 32 + l15)      * 72 + off];
                short8 a1 = *(const short8*)&Ap[(wm * 32 + 16 + l15) * 72 + off];
                short8 w0 = *(const short8*)&Wp[(wn * 32 + l15)      * 72 + off];
                short8 w1 = *(const short8*)&Wp[(wn * 32 + 16 + l15) * 72 + off];
                acc[0][0] = __builtin_amdgcn_mfma_f32_16x16x32_bf16(a0, w0, acc[0][0], 0, 0, 0);
                acc[0][1] = __builtin_amdgcn_mfma_f32_16x16x32_bf16(a0, w1, acc[0][1], 0, 0, 0);
                acc[1][0] = __builtin_amdgcn_mfma_f32_16x16x32_bf16(a1, w0, acc[1][0], 0, 0, 0);
                acc[1][1] = __builtin_amdgcn_mfma_f32_16x16x32_bf16(a1, w1, acc[1][1], 0, 0, 0);
            }
        }
    }

    float bl[2];
    #pragma unroll
    for (int ni = 0; ni < 2; ++ni)
        bl[ni] = bias[nb * 64 + wn * 32 + ni * 16 + l15];

    __syncthreads();                 // frag reads done before E overwrites LDS
    float* E = (float*)LS;           // 64 x 68 fp32 = 17408 B
    #pragma unroll
    for (int mi = 0; mi < 2; ++mi)
        #pragma unroll
        for (int ni = 0; ni < 2; ++ni) {
            const int m = wm * 32 + mi * 16 + q4 * 4;   // C/D: row=(lane>>4)*4+r
            const int n = wn * 32 + ni * 16 + l15;      //      col=lane&15
            #pragma unroll
            for (int r = 0; r < 4; ++r)
                E[(m + r) * 68 + n] =
                    fast_exp2((acc[mi][ni][r] + bl[ni]) * TANH_PRESCALE);
        }
    __syncthreads();

    if (isSrc) {
        // h-quad-interleaved: spq[(nb*16+nq)*16384 + (mrow0+m)*4 + (n&3)]
        const int nq = tid >> 4;                     // 0..15
        #pragma unroll
        for (int j = 0; j < 4; ++j) {
            const int m = (tid & 15) + 16 * j;       // 0..63
            float4 v = *(const float4*)&E[m * 68 + nq * 4];
            *(float4*)(spq + (size_t)(nb * 16 + nq) * 16384
                           + (size_t)(mrow0 + m) * 4) = v;
        }
    } else {
        // row-major qp[(mrow0+m)*256 + nb*64 + n]
        #pragma unroll
        for (int p = 0; p < 4; ++p) {
            const int idx = p * 256 + tid;
            const int m = idx >> 4, c4 = idx & 15;
            float4 v = *(const float4*)&E[m * 68 + c4 * 4];
            *(float4*)(qp + (size_t)(mrow0 + m) * 256 + nb * 64 + c4 * 4) = v;
        }
    }
}

// ---------------------------------------------------------------------------
// Fused score + masked softmax. Grid (32,16), 512 thr (8 waves).
// Mask-compacted s slots (execz skip when nU<=64) + pair-2 rcp fusion.
// R6: 4-deep register prefetch (p0..p3) on the strided spq loads — covers
// ~600-800 cyc of L3 latency with unrolled compute, vs 1 body (~150 cyc)
// before. All prefetch regs named, all indices compile-time.
// ---------------------------------------------------------------------------
__global__ __launch_bounds__(512) void attn_score(
    const float* __restrict__ spq, const float* __restrict__ qp,
    const float* __restrict__ w2, const int* __restrict__ mask,
    float* __restrict__ out)
{
    const int b  = blockIdx.x;   // 0..31
    const int tz = blockIdx.y;   // 0..15
    const int tid = threadIdx.x;

    __shared__ float qp_s[4][256];
    __shared__ float w2_s[256];
    __shared__ float h2p[4][4][128];   // [h-group][t-local][compacted s]
    __shared__ int   list_s[128];      // compacted -> original s
    __shared__ int   inv_s[128];       // original s -> compacted (-1 masked)
    __shared__ int   cnt_s[2];
    __shared__ int   nU_s;

    // --- staging: qp rows, w2, mask ballot-compaction ---
    int keep = 0, pre = 0, w01 = 0;
    if (tid < 256) {
        const int tl = tid >> 6, lane = tid & 63;
        const int t = tz * 4 + tl;
        *(float4*)&qp_s[tl][lane * 4] =
            *(const float4*)(qp + (size_t)(t * 32 + b) * 256 + lane * 4);
    } else if (tid < 320) {
        const int i = tid - 256;
        *(float4*)&w2_s[i * 4] = *(const float4*)(w2 + i * 4);
    }
    if (tid < 128) {                       // waves 0,1 fully present
        w01  = tid >> 6;
        keep = !mask[b * 128 + tid];
        const unsigned long long bal = __ballot(keep);
        pre  = __popcll(bal & ((1ull << (tid & 63)) - 1ull));
        if ((tid & 63) == 0) cnt_s[w01] = (int)__popcll(bal);
        inv_s[tid] = -1;
    }
    __syncthreads();
    if (tid < 128 && keep) {
        const int pos = (w01 ? cnt_s[0] : 0) + pre;
        list_s[pos] = tid;
        inv_s[tid]  = pos;
    }
    if (tid == 0) nU_s = cnt_s[0] + cnt_s[1];
    __syncthreads();

    const int j  = tid & 127;          // compacted s slot
    const int g  = tid >> 7;           // 0..3 -> h in [g*64, g*64+64)
    const int hb = g * 64;
    const int nU = nU_s;

    if (j < nU) {                      // whole-wave execz skip when nU<=64
        const int s = list_s[j];
        const float* sq = spq + (size_t)(g * 16) * 16384
                              + (size_t)(b * 128 + s) * 4;

        float acc0 = 0.f, acc1 = 0.f, acc2 = 0.f, acc3 = 0.f;

        // pair-2: w0/d0 + w1/d1 = (w0*d1 + w1*d0) * rcp(d0*d1)
        #define PN_PAIR(sa, sb, wa, wb, qa, qb, accv)                     \
            { float da = fmaf(sa, qa, 1.0f);                              \
              float db = fmaf(sb, qb, 1.0f);                              \
              float nm = fmaf(wa, db, wb * da);                           \
              accv = fmaf(nm, fast_rcp(da * db), accv); }
        #define PN_BODY(sv, hq_)                                          \
            { float4 w4 = *(const float4*)&w2_s[hb + (hq_) * 4];          \
              float4 q0 = *(const float4*)&qp_s[0][hb + (hq_) * 4];       \
              float4 q1 = *(const float4*)&qp_s[1][hb + (hq_) * 4];       \
              float4 q2 = *(const float4*)&qp_s[2][hb + (hq_) * 4];       \
              float4 q3 = *(const float4*)&qp_s[3][hb + (hq_) * 4];       \
              PN_PAIR(sv.x, sv.y, w4.x, w4.y, q0.x, q0.y, acc0)           \
              PN_PAIR(sv.x, sv.y, w4.x, w4.y, q1.x, q1.y, acc1)           \
              PN_PAIR(sv.x, sv.y, w4.x, w4.y, q2.x, q2.y, acc2)           \
              PN_PAIR(sv.x, sv.y, w4.x, w4.y, q3.x, q3.y, acc3)           \
              PN_PAIR(sv.z, sv.w, w4.z, w4.w, q0.z, q0.w, acc0)           \
              PN_PAIR(sv.z, sv.w, w4.z, w4.w, q1.z, q1.w, acc1)           \
              PN_PAIR(sv.z, sv.w, w4.z, w4.w, q2.z, q2.w, acc2)           \
              PN_PAIR(sv.z, sv.w, w4.z, w4.w, q3.z, q3.w, acc3) }
        #define LD(i) (*(const float4*)(sq + (size_t)(i) * 16384))

        // 4-deep rolling prefetch, fully static.
        float4 p0 = LD(0), p1 = LD(1), p2 = LD(2), p3 = LD(3);
        #pragma unroll
        for (int u = 0; u < 3; ++u) {
            PN_BODY(p0, u * 4 + 0)  p0 = LD(u * 4 + 4);
            PN_BODY(p1, u * 4 + 1)  p1 = LD(u * 4 + 5);
            PN_BODY(p2, u * 4 + 2)  p2 = LD(u * 4 + 6);
            PN_BODY(p3, u * 4 + 3)  p3 = LD(u * 4 + 7);
        }
        PN_BODY(p0, 12)
        PN_BODY(p1, 13)
        PN_BODY(p2, 14)
        PN_BODY(p3, 15)
        #undef LD
        #undef PN_BODY
        #undef PN_PAIR

        h2p[g][0][j] = acc0;
        h2p[g][1][j] = acc1;
        h2p[g][2][j] = acc2;
        h2p[g][3][j] = acc3;
    }
    __syncthreads();

    if (tid < 256) {
        const int wv = tid >> 6, lane = tid & 63;
        const int j0 = inv_s[lane], j1 = inv_s[lane + 64];
        float v0 = -__builtin_inff(), v1 = -__builtin_inff();
        if (j0 >= 0) v0 = -2.0f * (h2p[0][wv][j0] + h2p[1][wv][j0]
                                 + h2p[2][wv][j0] + h2p[3][wv][j0]);
        if (j1 >= 0) v1 = -2.0f * (h2p[0][wv][j1] + h2p[1][wv][j1]
                                 + h2p[2][wv][j1] + h2p[3][wv][j1]);

        float mx = fmaxf(v0, v1);
        #pragma unroll
        for (int off = 32; off >= 1; off >>= 1) mx = fmaxf(mx, __shfl_xor(mx, off));
        float e0 = fast_exp2((v0 - mx) * LOG2E);   // -inf -> 0
        float e1 = fast_exp2((v1 - mx) * LOG2E);
        float sum = e0 + e1;
        #pragma unroll
        for (int off = 32; off >= 1; off >>= 1) sum += __shfl_xor(sum, off);
        const float r = fast_rcp(sum);

        const size_t ob = (size_t)((tz * 4 + wv) * 32 + b) * 128;
        out[ob + lane]      = e0 * r;
        out[ob + lane + 64] = e1 * r;
    }
}

extern "C" void kernel_launch(void* const* d_in, const int* in_sizes, int n_in,
                              void* d_out, int out_size, void* d_ws, size_t ws_size,
                              hipStream_t stream) {
    const float* src   = (const float*)d_in[0];   // (B,S,E)
    const int*   mask  = (const int*)  d_in[1];   // (B,S)
    const float* query = (const float*)d_in[2];   // (T,B,Q)
    const float* W_src = (const float*)d_in[3];   // (H,E)
    const float* b_src = (const float*)d_in[4];
    const float* W_q   = (const float*)d_in[5];   // (H,Q)
    const float* b_q   = (const float*)d_in[6];
    const float* w2    = (const float*)d_in[7];
    // d_in[8] = b2 : unused (softmax shift-invariant)
    float* out = (float*)d_out;

    // ws: spq 4 MB @0 | qp 2 MB @4MB  (minimal footprint — ws is poisoned
    // with 256 MB of 0xAA every iteration; extra ws traffic is cold misses)
    float* spq = (float*)d_ws;
    float* qp  = (float*)((char*)d_ws + (4u << 20));

    proj_gemm<<<dim3(96, 4), 256, 0, stream>>>(src, query, W_src, W_q,
                                               b_src, b_q, spq, qp);
    attn_score<<<dim3(32, 16), 512, 0, stream>>>(spq, qp, w2, mask, out);
}

// Round 5
// 94.559 us; speedup vs baseline: 1.0647x; 1.0524x over previous
//
#include <hip/hip_runtime.h>
#include <hip/hip_bf16.h>
#include <math.h>

// ---------------------------------------------------------------------------
// PointerNet attention scorer, MI355X / gfx950.
//   1) proj_gemm: C = exp2(scale*(A@W^T + bias)) on bf16 MFMA with in-staging
//      fp32->bf16 hi/lo split (3 passes, rel err ~2^-16). Tile 64m x 64n,
//      grid (96,4), 256 thr, single-buffered LDS. src -> spq h-quad-
//      interleaved, query -> qp row-major. Epilogue stores exp2(val).
//      (R3 XCD remap reverted: 2-D grid already co-locates reuse per XCD.)
//   2) attn_score: logit ~ -2*sum_h w2[h]/(es*eq+1), masked softmax, S=128.
//      R7: R4's 4-deep prefetch REVERTED (-3.3us: likely VGPR >128 ->
//      1 block/CU). Back to R2's 1-deep loop. NEW: flattened work layout
//      g=tid&3, slot=tid>>2 -> the 4*nU mask-compacted items pack into the
//      lowest threads; active waves = ceil(nU/16) in {1..8} instead of
//      4*ceil(nU/64) in {4,8}. Fixes the wave-quantization tail that made
//      R2's mask-skip save ~0 wall time (E[waves|2 blocks/CU] 6.9 -> 4.8).
//      LDS g-padded (stride 68 / 516) so interleaved g-groups hit distinct
//      banks (avoids 4-way conflicts the flattening would otherwise cause).
// ---------------------------------------------------------------------------

#define TANH_PRESCALE 2.8853900817779268f   // 2*log2(e)
#define LOG2E        1.4426950408889634f

typedef __attribute__((ext_vector_type(8))) short short8;   // 8 bf16 = 4 VGPR
typedef __attribute__((ext_vector_type(4))) float f32x4;    // MFMA C/D frag

__device__ __forceinline__ float fast_exp2(float x) {
#if __has_builtin(__builtin_amdgcn_exp2f)
    return __builtin_amdgcn_exp2f(x);
#else
    return exp2f(x);
#endif
}
__device__ __forceinline__ float fast_rcp(float x) {
#if __has_builtin(__builtin_amdgcn_rcpf)
    return __builtin_amdgcn_rcpf(x);
#else
    return 1.0f / x;
#endif
}
__device__ __forceinline__ float hi_part(float x) {   // truncate to bf16 grid
    return __uint_as_float(__float_as_uint(x) & 0xffff0000u);
}
// pack bf16(a)=low16, bf16(b)=high16 (truncating) in one v_perm
__device__ __forceinline__ unsigned pack2(float a, float b) {
    return __builtin_amdgcn_perm(__float_as_uint(b), __float_as_uint(a), 0x07060302u);
}

// ---------------------------------------------------------------------------
// proj_gemm — R2-proven mechanics, original 2-D grid (96,4).
// ---------------------------------------------------------------------------
#define AHI 0
#define ALO 4608            // 64*72
#define WHI 9216
#define WLO 13824
#define LDS_USH 18432       // 36864 B

__global__ __launch_bounds__(256) void proj_gemm(
    const float* __restrict__ src, const float* __restrict__ query,
    const float* __restrict__ Wsrc, const float* __restrict__ Wq,
    const float* __restrict__ b_src, const float* __restrict__ b_q,
    float* __restrict__ spq, float* __restrict__ qp)
{
    const int bx = blockIdx.x;        // 0..95
    const int nb = blockIdx.y;        // 0..3
    const bool isSrc = bx < 64;
    const int mrow0 = (isSrc ? bx : bx - 64) * 64;
    const float* __restrict__ A    = isSrc ? src  : query;
    const float* __restrict__ W    = isSrc ? Wsrc : Wq;
    const float* __restrict__ bias = isSrc ? b_src : b_q;

    __shared__ unsigned short LS[LDS_USH];

    const int tid  = threadIdx.x;
    const int lane = tid & 63;
    const int wv   = tid >> 6;
    const int wm   = wv & 1, wn = wv >> 1;
    const int l15  = lane & 15;
    const int q4   = lane >> 4;       // 0..3

    const int srow = tid >> 3;        // rows for p=0 (0..31); p=1 adds 32
    const int sc8  = tid & 7;

    f32x4 acc[2][2];
    #pragma unroll
    for (int i = 0; i < 2; ++i)
        #pragma unroll
        for (int j = 0; j < 2; ++j) acc[i][j] = (f32x4){0.f, 0.f, 0.f, 0.f};

    const float* Ab = A + (size_t)mrow0 * 512 + sc8 * 8;
    const float* Wb = W + (size_t)(nb * 64) * 512 + sc8 * 8;

    for (int kt = 0; kt < 512; kt += 64) {
        __syncthreads();   // previous tile's frag reads done
        #pragma unroll
        for (int p = 0; p < 2; ++p) {          // A: 64 rows x 64 k
            const int row = srow + 32 * p;
            const float* g = Ab + (size_t)row * 512 + kt;
            float4 v0 = *(const float4*)g, v1 = *(const float4*)(g + 4);
            uint4 h; uint4 l;
            h.x = pack2(v0.x, v0.y);  h.y = pack2(v0.z, v0.w);
            h.z = pack2(v1.x, v1.y);  h.w = pack2(v1.z, v1.w);
            l.x = pack2(v0.x - hi_part(v0.x), v0.y - hi_part(v0.y));
            l.y = pack2(v0.z - hi_part(v0.z), v0.w - hi_part(v0.w));
            l.z = pack2(v1.x - hi_part(v1.x), v1.y - hi_part(v1.y));
            l.w = pack2(v1.z - hi_part(v1.z), v1.w - hi_part(v1.w));
            *(uint4*)&LS[AHI + row * 72 + sc8 * 8] = h;
            *(uint4*)&LS[ALO + row * 72 + sc8 * 8] = l;
        }
        #pragma unroll
        for (int p = 0; p < 2; ++p) {          // W: 64 rows x 64 k
            const int row = srow + 32 * p;
            const float* g = Wb + (size_t)row * 512 + kt;
            float4 v0 = *(const float4*)g, v1 = *(const float4*)(g + 4);
            uint4 h; uint4 l;
            h.x = pack2(v0.x, v0.y);  h.y = pack2(v0.z, v0.w);
            h.z = pack2(v1.x, v1.y);  h.w = pack2(v1.z, v1.w);
            l.x = pack2(v0.x - hi_part(v0.x), v0.y - hi_part(v0.y));
            l.y = pack2(v0.z - hi_part(v0.z), v0.w - hi_part(v0.w));
            l.z = pack2(v1.x - hi_part(v1.x), v1.y - hi_part(v1.y));
            l.w = pack2(v1.z - hi_part(v1.z), v1.w - hi_part(v1.w));
            *(uint4*)&LS[WHI + row * 72 + sc8 * 8] = h;
            *(uint4*)&LS[WLO + row * 72 + sc8 * 8] = l;
        }
        __syncthreads();

        #pragma unroll
        for (int pass = 0; pass < 3; ++pass) {
            const unsigned short* Ap = LS + (pass == 2 ? ALO : AHI);
            const unsigned short* Wp = LS + (pass == 1 ? WLO : WHI);
            #pragma unroll
            for (int kk = 0; kk < 2; ++kk) {
                const int off = (kk * 4 + q4) * 8;    // ushort k-octet offset
                short8 a0 = *(const short8*)&Ap[(wm * 32 + l15)      * 72 + off];
                short8 a1 = *(const short8*)&Ap[(wm * 32 + 16 + l15) * 72 + off];
                short8 w0 = *(const short8*)&Wp[(wn * 32 + l15)      * 72 + off];
                short8 w1 = *(const short8*)&Wp[(wn * 32 + 16 + l15) * 72 + off];
                acc[0][0] = __builtin_amdgcn_mfma_f32_16x16x32_bf16(a0, w0, acc[0][0], 0, 0, 0);
                acc[0][1] = __builtin_amdgcn_mfma_f32_16x16x32_bf16(a0, w1, acc[0][1], 0, 0, 0);
                acc[1][0] = __builtin_amdgcn_mfma_f32_16x16x32_bf16(a1, w0, acc[1][0], 0, 0, 0);
                acc[1][1] = __builtin_amdgcn_mfma_f32_16x16x32_bf16(a1, w1, acc[1][1], 0, 0, 0);
            }
        }
    }

    float bl[2];
    #pragma unroll
    for (int ni = 0; ni < 2; ++ni)
        bl[ni] = bias[nb * 64 + wn * 32 + ni * 16 + l15];

    __syncthreads();                 // frag reads done before E overwrites LDS
    float* E = (float*)LS;           // 64 x 68 fp32 = 17408 B
    #pragma unroll
    for (int mi = 0; mi < 2; ++mi)
        #pragma unroll
        for (int ni = 0; ni < 2; ++ni) {
            const int m = wm * 32 + mi * 16 + q4 * 4;   // C/D: row=(lane>>4)*4+r
            const int n = wn * 32 + ni * 16 + l15;      //      col=lane&15
            #pragma unroll
            for (int r = 0; r < 4; ++r)
                E[(m + r) * 68 + n] =
                    fast_exp2((acc[mi][ni][r] + bl[ni]) * TANH_PRESCALE);
        }
    __syncthreads();

    if (isSrc) {
        // h-quad-interleaved: spq[(nb*16+nq)*16384 + (mrow0+m)*4 + (n&3)]
        const int nq = tid >> 4;                     // 0..15
        #pragma unroll
        for (int j = 0; j < 4; ++j) {
            const int m = (tid & 15) + 16 * j;       // 0..63
            float4 v = *(const float4*)&E[m * 68 + nq * 4];
            *(float4*)(spq + (size_t)(nb * 16 + nq) * 16384
                           + (size_t)(mrow0 + m) * 4) = v;
        }
    } else {
        // row-major qp[(mrow0+m)*256 + nb*64 + n]
        #pragma unroll
        for (int p = 0; p < 4; ++p) {
            const int idx = p * 256 + tid;
            const int m = idx >> 4, c4 = idx & 15;
            float4 v = *(const float4*)&E[m * 68 + c4 * 4];
            *(float4*)(qp + (size_t)(mrow0 + m) * 256 + nb * 64 + c4 * 4) = v;
        }
    }
}

// ---------------------------------------------------------------------------
// Fused score + masked softmax. Grid (32,16), 512 thr (8 waves).
// Flattened work: thread -> (g = tid&3, slot jj = tid>>2). Active waves =
// ceil(nU/16) instead of {4,8}. LDS g-padded: h index -> (h>>6)*68+(h&63)
// so the 4 interleaved g-groups read distinct banks. Inner loop = R2's
// proven 1-deep prefetch + pair-2 rcp, byte-identical math.
// ---------------------------------------------------------------------------
__global__ __launch_bounds__(512) void attn_score(
    const float* __restrict__ spq, const float* __restrict__ qp,
    const float* __restrict__ w2, const int* __restrict__ mask,
    float* __restrict__ out)
{
    const int b  = blockIdx.x;   // 0..31
    const int tz = blockIdx.y;   // 0..15
    const int tid = threadIdx.x;

    __shared__ float qp_s[4][272];     // [t-local][g*68 + hh]
    __shared__ float w2_s[272];
    __shared__ float h2p[4][516];      // [g][tl*128 + slot], g-stride 516
    __shared__ int   list_s[128];      // compacted slot -> original s
    __shared__ int   inv_s[128];       // original s -> slot (-1 masked)
    __shared__ int   cnt_s[2];
    __shared__ int   nU_s;

    // --- staging: qp rows, w2, mask ballot-compaction ---
    int keep = 0, pre = 0, w01 = 0;
    if (tid < 256) {
        const int tl = tid >> 6, lane = tid & 63;
        const int t = tz * 4 + tl;
        const int di = lane * 4 + (lane >> 4) * 4;   // g-padded dest
        *(float4*)&qp_s[tl][di] =
            *(const float4*)(qp + (size_t)(t * 32 + b) * 256 + lane * 4);
    } else if (tid < 320) {
        const int i = tid - 256;
        const int di = i * 4 + (i >> 4) * 4;
        *(float4*)&w2_s[di] = *(const float4*)(w2 + i * 4);
    }
    if (tid < 128) {                       // waves 0,1 fully present
        w01  = tid >> 6;
        keep = !mask[b * 128 + tid];
        const unsigned long long bal = __ballot(keep);
        pre  = __popcll(bal & ((1ull << (tid & 63)) - 1ull));
        if ((tid & 63) == 0) cnt_s[w01] = (int)__popcll(bal);
        inv_s[tid] = -1;
    }
    __syncthreads();
    if (tid < 128 && keep) {
        const int pos = (w01 ? cnt_s[0] : 0) + pre;
        list_s[pos] = tid;
        inv_s[tid]  = pos;
    }
    if (tid == 0) nU_s = cnt_s[0] + cnt_s[1];
    __syncthreads();

    const int g  = tid & 3;            // h-group
    const int jj = tid >> 2;           // compacted s slot 0..127
    const int hb = g * 68;             // padded base into qp_s/w2_s
    const int nU = nU_s;

    if (jj < nU) {                     // waves with 16*w >= nU skip via execz
        const int s = list_s[jj];
        const float* sq = spq + (size_t)(g * 16) * 16384
                              + (size_t)(b * 128 + s) * 4;

        float acc0 = 0.f, acc1 = 0.f, acc2 = 0.f, acc3 = 0.f;
        float4 s4 = *(const float4*)sq;                 // prefetch hq=0
        #pragma unroll 4
        for (int hq = 0; hq < 16; ++hq) {
            float4 nxt;
            if (hq < 15) nxt = *(const float4*)(sq + (size_t)(hq + 1) * 16384);
            float4 w4 = *(const float4*)&w2_s[hb + hq * 4];
            float4 q0 = *(const float4*)&qp_s[0][hb + hq * 4];
            float4 q1 = *(const float4*)&qp_s[1][hb + hq * 4];
            float4 q2 = *(const float4*)&qp_s[2][hb + hq * 4];
            float4 q3 = *(const float4*)&qp_s[3][hb + hq * 4];
            // pair-2: w0/d0 + w1/d1 = (w0*d1 + w1*d0) * rcp(d0*d1)
            #define PN_PAIR(sa, sb, wa, wb, qa, qb, accv)                     \
                { float da = fmaf(sa, qa, 1.0f);                              \
                  float db = fmaf(sb, qb, 1.0f);                              \
                  float nm = fmaf(wa, db, wb * da);                           \
                  accv = fmaf(nm, fast_rcp(da * db), accv); }
            PN_PAIR(s4.x, s4.y, w4.x, w4.y, q0.x, q0.y, acc0)
            PN_PAIR(s4.x, s4.y, w4.x, w4.y, q1.x, q1.y, acc1)
            PN_PAIR(s4.x, s4.y, w4.x, w4.y, q2.x, q2.y, acc2)
            PN_PAIR(s4.x, s4.y, w4.x, w4.y, q3.x, q3.y, acc3)
            PN_PAIR(s4.z, s4.w, w4.z, w4.w, q0.z, q0.w, acc0)
            PN_PAIR(s4.z, s4.w, w4.z, w4.w, q1.z, q1.w, acc1)
            PN_PAIR(s4.z, s4.w, w4.z, w4.w, q2.z, q2.w, acc2)
            PN_PAIR(s4.z, s4.w, w4.z, w4.w, q3.z, q3.w, acc3)
            #undef PN_PAIR
            s4 = nxt;
        }
        h2p[g][0 * 128 + jj] = acc0;
        h2p[g][1 * 128 + jj] = acc1;
        h2p[g][2 * 128 + jj] = acc2;
        h2p[g][3 * 128 + jj] = acc3;
    }
    __syncthreads();

    if (tid < 256) {
        const int wv = tid >> 6, lane = tid & 63;
        const int j0 = inv_s[lane], j1 = inv_s[lane + 64];
        float v0 = -__builtin_inff(), v1 = -__builtin_inff();
        if (j0 >= 0) v0 = -2.0f * (h2p[0][wv * 128 + j0] + h2p[1][wv * 128 + j0]
                                 + h2p[2][wv * 128 + j0] + h2p[3][wv * 128 + j0]);
        if (j1 >= 0) v1 = -2.0f * (h2p[0][wv * 128 + j1] + h2p[1][wv * 128 + j1]
                                 + h2p[2][wv * 128 + j1] + h2p[3][wv * 128 + j1]);

        float mx = fmaxf(v0, v1);
        #pragma unroll
        for (int off = 32; off >= 1; off >>= 1) mx = fmaxf(mx, __shfl_xor(mx, off));
        float e0 = fast_exp2((v0 - mx) * LOG2E);   // -inf -> 0
        float e1 = fast_exp2((v1 - mx) * LOG2E);
        float sum = e0 + e1;
        #pragma unroll
        for (int off = 32; off >= 1; off >>= 1) sum += __shfl_xor(sum, off);
        const float r = fast_rcp(sum);

        const size_t ob = (size_t)((tz * 4 + wv) * 32 + b) * 128;
        out[ob + lane]      = e0 * r;
        out[ob + lane + 64] = e1 * r;
    }
}

extern "C" void kernel_launch(void* const* d_in, const int* in_sizes, int n_in,
                              void* d_out, int out_size, void* d_ws, size_t ws_size,
                              hipStream_t stream) {
    const float* src   = (const float*)d_in[0];   // (B,S,E)
    const int*   mask  = (const int*)  d_in[1];   // (B,S)
    const float* query = (const float*)d_in[2];   // (T,B,Q)
    const float* W_src = (const float*)d_in[3];   // (H,E)
    const float* b_src = (const float*)d_in[4];
    const float* W_q   = (const float*)d_in[5];   // (H,Q)
    const float* b_q   = (const float*)d_in[6];
    const float* w2    = (const float*)d_in[7];
    // d_in[8] = b2 : unused (softmax shift-invariant)
    float* out = (float*)d_out;

    // ws: spq 4 MB @0 | qp 2 MB @4MB  (minimal footprint — ws is poisoned
    // with 256 MB of 0xAA every iteration; extra ws traffic is cold misses)
    float* spq = (float*)d_ws;
    float* qp  = (float*)((char*)d_ws + (4u << 20));

    proj_gemm<<<dim3(96, 4), 256, 0, stream>>>(src, query, W_src, W_q,
                                               b_src, b_q, spq, qp);
    attn_score<<<dim3(32, 16), 512, 0, stream>>>(spq, qp, w2, mask, out);
}